// Round 9
// baseline (380.557 us; speedup 1.0000x reference)
//
#include <hip/hip_runtime.h>
#include <cstdint>
#include <cstddef>

constexpr int kC = 1024;   // DIM
constexpr int kH = 16;     // heads
constexpr int kB = 4;      // batch
constexpr int kN = 2048;   // seq
constexpr int kD = 64;     // head dim

// softmax scale folded into Q at the QKV-GEMM epilogue: 0.125 * log2(e)
#define KQ_SCALE 0.18033688011112042f

typedef unsigned short u16;
typedef unsigned int   u32;
typedef unsigned long long u64;
typedef __bf16 v8bf  __attribute__((ext_vector_type(8)));
typedef float  v4f   __attribute__((ext_vector_type(4)));
typedef u16    u16x8 __attribute__((ext_vector_type(8)));
typedef u16    u16x4 __attribute__((ext_vector_type(4)));

__device__ inline u16 f2bf(float f) {
    union { float f; unsigned u; } v; v.f = f;
    unsigned r = v.u + 0x7FFFu + ((v.u >> 16) & 1u);   // RNE
    return (u16)(r >> 16);
}

__device__ inline float fast_exp2(float x) {
#if __has_builtin(__builtin_amdgcn_exp2f)
    return __builtin_amdgcn_exp2f(x);          // bare v_exp_f32
#else
    return __expf(x * 0.6931471805599453f);
#endif
}

// async 16B global -> LDS (wave-uniform LDS base + lane*16)
__device__ inline void gl2lds16(const u16* g, u16* l) {
    __builtin_amdgcn_global_load_lds(
        (const __attribute__((address_space(1))) void*)g,
        (__attribute__((address_space(3))) void*)l, 16, 0, 0);
}

// ---------------------------------------------------------------- casts
__global__ __launch_bounds__(256) void cast_bf16_kernel(
    const float* __restrict__ in, u16* __restrict__ outp)
{
    const int i = blockIdx.x * 256 + threadIdx.x;
    const float4 f = ((const float4*)in)[i];
    u16x4 o;
    o.x = f2bf(f.x); o.y = f2bf(f.y); o.z = f2bf(f.z); o.w = f2bf(f.w);
    ((u16x4*)outp)[i] = o;
}

// W [R][Cc] fp32 -> Wt [Cc][R] bf16, 64x64 LDS tiles
__global__ __launch_bounds__(256) void tpose_cast_kernel(
    const float* __restrict__ W, u16* __restrict__ Wt, int R, int Cc)
{
    __shared__ u16 tile[64][65];
    const int c0 = blockIdx.x * 64;
    const int r0 = blockIdx.y * 64;
    const int t  = threadIdx.x;
#pragma unroll
    for (int it = 0; it < 16; ++it) {
        const int r = it * 4 + (t >> 6);
        const int c = t & 63;
        tile[c][r] = f2bf(W[(size_t)(r0 + r) * Cc + c0 + c]);
    }
    __syncthreads();
#pragma unroll
    for (int it = 0; it < 16; ++it) {
        const int rr = it * 4 + (t >> 6);
        const int cc = t & 63;
        Wt[(size_t)(c0 + rr) * R + r0 + cc] = tile[rr][cc];
    }
}

// ------------------------------------------------------------ mask pack
// Grid-strided: 2048 blocks. Row-bitmap: row (b*N+q) is 2048 bits
// (64 u32), bit k set iff masked. (R5-proven version.)
__global__ __launch_bounds__(256) void maskpack_kernel(
    const int* __restrict__ mask, u32* __restrict__ bits)
{
    const int lane = threadIdx.x & 63;
    const int wv   = threadIdx.x >> 6;
    const int nseg = kB * kN * 32;
    for (int seg = blockIdx.x * 4 + wv; seg < nseg; seg += gridDim.x * 4) {
        const size_t row = (size_t)(seg >> 5);   // b*N + q
        const int s = seg & 31;                  // 64-key segment within row
        const int m = mask[row * kN + s * 64 + lane];
        const u64 bal = __ballot(m != 0);
        if (lane == 0) ((u64*)bits)[row * 32 + s] = bal;
    }
}

// ------------------------------------------- 256x256 8-phase MFMA GEMM
// C[M,N] = A[M,K] @ Bt[N,K]^T + bias. Tile 256x256, BK=64, 512 threads
// (8 waves, 2M x 4N; wave owns 128x64 = acc[8][4]). LDS 128 KB: 2 dbuf x
// {A 256x64, B 256x64}. Per K-tile, 4 phases:
//   p0: stage A-halves(next) ; vmcnt(4) ; s_barrier (publish cur tile) ;
//       ds_read B-frags(8)+A-frags(4) ; setprio(1) MFMA x16 setprio(0) ;
//       s_barrier
//   p1: ds_read A(4) ; stage B-halves(next) ; barrier ; MFMA x16 ; barrier
//   p2/p3: ds_read A(4) ; barrier ; MFMA x16 ; barrier
// Counted vmcnt(4) ONCE per K-tile, never 0 in main loop (T3+T4): the 8
// loads of tile t (issued in t-1 p0/p1) retire while the 4 just-issued fly.
// Staging issued phases 0-1 -> ~3 phase-times of flight before use.
// Hazards: RAW = vmcnt(4) + publish barrier (all waves' gl2lds landed).
// WAR = buf[nxt] written at t was last ds_read before t-1's final barrier.
// Swizzle (T2, rule #21 both-sides): LDS row r chunk-slot p holds global
// chunk p^(r&7) (pre-swizzled per-lane SOURCE addr; LDS dest linear);
// reads at chunk (kk*4+quad)^(l16&7) -> 16 lanes hit 8 chunks x 2 = free.
template <int MODE>
__global__ __launch_bounds__(512, 2) void gemm256_kernel(
    const u16* __restrict__ A, const u16* __restrict__ Bt,
    const float* __restrict__ bias, float* __restrict__ Cout,
    u16* __restrict__ qOut, u16* __restrict__ kOut, u16* __restrict__ vOut,
    int M, int N, int K)
{
    __shared__ u16 lds[2][2][16384];   // [buf][A/B][half*8192 + slot*8]

    const int t    = threadIdx.x;      // 0..511
    const int w    = t >> 6;
    const int lane = t & 63;
    const int quad = lane >> 4;
    const int l16  = lane & 15;
    const int wm   = w >> 2;           // 0..1
    const int wn   = w & 3;            // 0..3

    // XCD-chunked bijective swizzle (nwg % 8 == 0), column-major walk
    const int nbm = M >> 8;
    const int q8  = (int)gridDim.x >> 3;
    const int bid = (int)blockIdx.x;
    const int swz = (bid & 7) * q8 + (bid >> 3);
    const int m0  = (swz % nbm) * 256;
    const int n0  = (swz / nbm) * 256;

    // staging sources: slot s = L*512 + t ; r = s>>3 (0..127) ; p = s&7 ;
    // source col-chunk = p ^ (r&7)  (involution with the read swizzle)
    const size_t halfStep = (size_t)128 * K;
    const int s0 = t, s1 = 512 + t;
    const int r0 = s0 >> 3, r1 = s1 >> 3;
    const int c0 = ((s0 & 7) ^ (r0 & 7)) * 8;
    const int c1 = ((s1 & 7) ^ (r1 & 7)) * 8;
    const u16* gA0 = A  + (size_t)(m0 + r0) * K + c0;
    const u16* gA1 = A  + (size_t)(m0 + r1) * K + c1;
    const u16* gB0 = Bt + (size_t)(n0 + r0) * K + c0;
    const u16* gB1 = Bt + (size_t)(n0 + r1) * K + c1;

    v4f acc[8][4];
#pragma unroll
    for (int mi = 0; mi < 8; ++mi)
#pragma unroll
        for (int ni = 0; ni < 4; ++ni) acc[mi][ni] = (v4f){0.f, 0.f, 0.f, 0.f};

    const int aRowB = (wm * 128 + l16) * 64;   // + mi*1024
    const int bRowB = (wn * 64  + l16) * 64;   // + ni*1024
    const int ch0   = ((quad    ) ^ (l16 & 7)) * 8;   // kk=0 chunk
    const int ch1   = ((quad + 4) ^ (l16 & 7)) * 8;   // kk=1 chunk

    auto stageA = [&](int buf, int kt) {
        const int ko = kt * 64;
        gl2lds16(gA0 + ko,            &lds[buf][0][       w * 512]);
        gl2lds16(gA1 + ko,            &lds[buf][0][4096 + w * 512]);
        gl2lds16(gA0 + halfStep + ko, &lds[buf][0][8192        + w * 512]);
        gl2lds16(gA1 + halfStep + ko, &lds[buf][0][8192 + 4096 + w * 512]);
    };
    auto stageB = [&](int buf, int kt) {
        const int ko = kt * 64;
        gl2lds16(gB0 + ko,            &lds[buf][1][       w * 512]);
        gl2lds16(gB1 + ko,            &lds[buf][1][4096 + w * 512]);
        gl2lds16(gB0 + halfStep + ko, &lds[buf][1][8192        + w * 512]);
        gl2lds16(gB1 + halfStep + ko, &lds[buf][1][8192 + 4096 + w * 512]);
    };

    const int NT = K >> 6;   // 16 K-tiles
    stageA(0, 0);
    stageB(0, 0);

    for (int kt = 0; kt < NT; ++kt) {
        const int  cur  = kt & 1;
        const int  nxt  = cur ^ 1;
        const bool more = (kt + 1 < NT);
        v8bf bfr[4][2];

#pragma unroll
        for (int p = 0; p < 4; ++p) {
            if (p == 0) {
                if (more) stageA(nxt, kt + 1);
                if (more) asm volatile("s_waitcnt vmcnt(4)" ::: "memory");
                else      asm volatile("s_waitcnt vmcnt(0)" ::: "memory");
                __builtin_amdgcn_s_barrier();            // publish tile kt
                __builtin_amdgcn_sched_barrier(0);
#pragma unroll
                for (int ni = 0; ni < 4; ++ni) {
                    bfr[ni][0] = *(const v8bf*)(&lds[cur][1][bRowB + ni * 1024 + ch0]);
                    bfr[ni][1] = *(const v8bf*)(&lds[cur][1][bRowB + ni * 1024 + ch1]);
                }
            }
            v8bf a0[2], a1[2];
#pragma unroll
            for (int i = 0; i < 2; ++i) {
                a0[i] = *(const v8bf*)(&lds[cur][0][aRowB + (2 * p + i) * 1024 + ch0]);
                a1[i] = *(const v8bf*)(&lds[cur][0][aRowB + (2 * p + i) * 1024 + ch1]);
            }
            if (p == 1 && more) stageB(nxt, kt + 1);
            if (p != 0) {
                __builtin_amdgcn_s_barrier();
                __builtin_amdgcn_sched_barrier(0);
            }
            __builtin_amdgcn_s_setprio(1);
#pragma unroll
            for (int i = 0; i < 2; ++i)
#pragma unroll
                for (int ni = 0; ni < 4; ++ni) {
                    acc[2 * p + i][ni] = __builtin_amdgcn_mfma_f32_16x16x32_bf16(
                        a0[i], bfr[ni][0], acc[2 * p + i][ni], 0, 0, 0);
                    acc[2 * p + i][ni] = __builtin_amdgcn_mfma_f32_16x16x32_bf16(
                        a1[i], bfr[ni][1], acc[2 * p + i][ni], 0, 0, 0);
                }
            __builtin_amdgcn_s_setprio(0);
            __builtin_amdgcn_s_barrier();
            __builtin_amdgcn_sched_barrier(0);
        }
    }

    // ---- epilogue
#pragma unroll
    for (int ni = 0; ni < 4; ++ni) {
        const int col = n0 + wn * 64 + ni * 16 + l16;
        const float bv = bias[col];
#pragma unroll
        for (int mi = 0; mi < 8; ++mi) {
#pragma unroll
            for (int reg = 0; reg < 4; ++reg) {
                const int row = m0 + wm * 128 + mi * 16 + quad * 4 + reg;
                float val = acc[mi][ni][reg] + bv;
                if (MODE == 0) {
                    Cout[(size_t)row * N + col] = val;
                } else {
                    const int which = col >> 10;
                    const int rem   = col & 1023;
                    const int h     = rem >> 6;
                    const int d     = rem & 63;
                    const int b     = row >> 11;
                    const int n     = row & 2047;
                    if (which == 0) val *= KQ_SCALE;   // fold softmax scale + log2e into Q
                    u16* dst = (which == 0) ? qOut : (which == 1) ? kOut : vOut;
                    dst[(((size_t)(b * kH + h)) * kN + n) * kD + d] = f2bf(val);
                }
            }
        }
    }
}

// ------------------------------------------------- MFMA attention (bf16)
// R5/R8-proven version, unchanged. Block = 128 q-rows of one (b,h);
// 4 waves, wave w owns q-rows w*32..+32. Double-buffered LDS (64 KB),
// one barrier per KV-tile. P stays in registers (permuted-k trick);
// row-sums via ones-MFMA; Q pre-scaled by 0.125*log2e.
__global__ __launch_bounds__(256, 2) void attn_mfma_kernel(
    const u16* __restrict__ q, const u16* __restrict__ k,
    const u16* __restrict__ v, const u32* __restrict__ mbits,
    u16* __restrict__ out)   // bf16 ao [B,N,C]
{
    __shared__ u16 Ks[2][128 * 64];   // 32 KB  [key][d], chunk ^= (key&7)
    __shared__ u16 Vt[2][64 * 128];   // 32 KB  [d][key-permuted], chunk ^= (d&15)

    const int t    = threadIdx.x;
    const int w    = t >> 6;
    const int lane = t & 63;
    const int quad = lane >> 4;
    const int l16  = lane & 15;

    const int bh    = blockIdx.x >> 4;          // 16 q-tiles of 128 rows
    const int tile0 = (blockIdx.x & 15) * 128;
    const int b     = bh >> 4;
    const int h     = bh & 15;

    const u16* qb = q + (size_t)bh * kN * kD;
    const u16* kb = k + (size_t)bh * kN * kD;
    const u16* vb = v + (size_t)bh * kN * kD;

    // Q B-fragments for 2 strips: lane holds Q[qrow][d = quad*8 + j]
    const int qrow0 = tile0 + w * 32 + l16;
    const int qrow1 = qrow0 + 16;
    v8bf qf[2][2];
    qf[0][0] = *(const v8bf*)(qb + (size_t)qrow0 * kD + quad * 8);
    qf[0][1] = *(const v8bf*)(qb + (size_t)qrow0 * kD + 32 + quad * 8);
    qf[1][0] = *(const v8bf*)(qb + (size_t)qrow1 * kD + quad * 8);
    qf[1][1] = *(const v8bf*)(qb + (size_t)qrow1 * kD + 32 + quad * 8);

    // staging geometry (constant per thread)
    // K: 2 rows x 32 dims per thread (4x 16B swizzled b128 writes)
    const int skr  = t >> 1;           // K row 0..127
    const int skh  = t & 1;            // K half (32 elems)
    // V: permuted 8 keys x 4 dims per thread -> 4x b128 transposed writes.
    const int vg   = t >> 4;           // frag chunk 0..15
    const int vdq  = t & 15;           // dim quad (dims vdq*4..+3)
    const int vrow0 = (vg >> 2) * 32 + (vg & 3) * 4;

    const u16* kp = kb + (size_t)skr * kD + skh * 32;
    const u16* vp = vb + (size_t)vrow0 * kD + vdq * 4;
    const uint4* mp0 = (const uint4*)(mbits + ((size_t)b * kN + qrow0) * 64);
    const uint4* mp1 = (const uint4*)(mbits + ((size_t)b * kN + qrow1) * 64);

    u16x8 kpre[4];
    u16x4 vpre[8];
    uint4 mpre0, mpre1;
    auto issue_prefetch = [&]() {
#pragma unroll
        for (int i = 0; i < 4; ++i)
            kpre[i] = *(const u16x8*)(kp + i * 8);
#pragma unroll
        for (int i = 0; i < 8; ++i)
            vpre[i] = *(const u16x4*)(vp + (i < 4 ? i * 64 : 1024 + (i - 4) * 64));
        mpre0 = *mp0; mpre1 = *mp1;
        kp += 128 * kD; vp += 128 * kD; ++mp0; ++mp1;
    };

    v8bf onesf;
#pragma unroll
    for (int j = 0; j < 8; ++j) onesf[j] = (__bf16)1.0f;

    v4f oacc[2][4];
    v4f rsacc[2];
#pragma unroll
    for (int qs = 0; qs < 2; ++qs) {
        rsacc[qs] = (v4f){0.f, 0.f, 0.f, 0.f};
#pragma unroll
        for (int i = 0; i < 4; ++i) oacc[qs][i] = (v4f){0.f, 0.f, 0.f, 0.f};
    }

    issue_prefetch();   // tile 0

    for (int kt = 0; kt < kN / 128; ++kt) {
        u16* KsB = Ks[kt & 1];
        u16* VtB = Vt[kt & 1];

        // ---- stage tile kt from regs into buf[kt&1]
        {
            const int cb = skh * 4;
            u16* drow = &KsB[skr * 64];
#pragma unroll
            for (int i = 0; i < 4; ++i)
                *(u16x8*)(&drow[((cb + i) ^ (skr & 7)) * 8]) = kpre[i];
        }
        {
#pragma unroll
            for (int dd = 0; dd < 4; ++dd) {
                const int d = vdq * 4 + dd;
                u16x8 col;
#pragma unroll
                for (int j = 0; j < 8; ++j) col[j] = vpre[j][dd];
                *(u16x8*)(&VtB[d * 128 + ((vg ^ (d & 15)) * 8)]) = col;
            }
        }
        const uint4 mc0 = mpre0, mc1 = mpre1;
        if (kt + 1 < kN / 128) issue_prefetch();   // regs free after ds_writes issue

        __syncthreads();   // publish buf[kt&1]; WAR covered by prev barrier

        const u32 mwa[2][4] = {{mc0.x, mc0.y, mc0.z, mc0.w},
                               {mc1.x, mc1.y, mc1.z, mc1.w}};
        v8bf pa[2][4];     // P A-fragments, built directly in registers

        // ---- S^T + softmax: lane gets s[reg] = S[key=nb*16+quad*4+reg][q=l16]
#pragma unroll
        for (int nb = 0; nb < 8; ++nb) {
            const int krow = nb * 16 + l16;
            const v8bf kf0 = *(const v8bf*)(&KsB[krow * 64 + ((quad       ^ (krow & 7)) * 8)]);
            const v8bf kf1 = *(const v8bf*)(&KsB[krow * 64 + (((quad + 4) ^ (krow & 7)) * 8)]);
#pragma unroll
            for (int qs = 0; qs < 2; ++qs) {
                v4f s = (v4f){0.f, 0.f, 0.f, 0.f};
                s = __builtin_amdgcn_mfma_f32_16x16x32_bf16(kf0, qf[qs][0], s, 0, 0, 0);
                s = __builtin_amdgcn_mfma_f32_16x16x32_bf16(kf1, qf[qs][1], s, 0, 0, 0);

                const u32 m4 = (mwa[qs][nb >> 1] >> ((nb & 1) * 16 + quad * 4)) & 0xFu;
                float e0 = fast_exp2(s[0]);
                float e1 = fast_exp2(s[1]);
                float e2 = fast_exp2(s[2]);
                float e3 = fast_exp2(s[3]);
                e0 = (m4 & 1u) ? 0.f : e0;
                e1 = (m4 & 2u) ? 0.f : e1;
                e2 = (m4 & 4u) ? 0.f : e2;
                e3 = (m4 & 8u) ? 0.f : e3;

                pa[qs][nb >> 1][(nb & 1) * 4 + 0] = (__bf16)e0;
                pa[qs][nb >> 1][(nb & 1) * 4 + 1] = (__bf16)e1;
                pa[qs][nb >> 1][(nb & 1) * 4 + 2] = (__bf16)e2;
                pa[qs][nb >> 1][(nb & 1) * 4 + 3] = (__bf16)e3;
            }
        }

        __builtin_amdgcn_s_setprio(1);
        // row-sums via ones-MFMA: rsacc row layout == oacc row layout
#pragma unroll
        for (int qs = 0; qs < 2; ++qs)
#pragma unroll
            for (int ks = 0; ks < 4; ++ks)
                rsacc[qs] = __builtin_amdgcn_mfma_f32_16x16x32_bf16(
                    pa[qs][ks], onesf, rsacc[qs], 0, 0, 0);
        // ---- PV: O[q][d] += P(32x128) @ V^T
#pragma unroll
        for (int ks = 0; ks < 4; ++ks)
#pragma unroll
            for (int db = 0; db < 4; ++db) {
                const int d = db * 16 + l16;
                const v8bf vf = *(const v8bf*)(&VtB[d * 128 + (((ks * 4 + quad) ^ (d & 15)) * 8)]);
#pragma unroll
                for (int qs = 0; qs < 2; ++qs)
                    oacc[qs][db] = __builtin_amdgcn_mfma_f32_16x16x32_bf16(
                        pa[qs][ks], vf, oacc[qs][db], 0, 0, 0);
            }
        __builtin_amdgcn_s_setprio(0);
    }

    // ---- normalize + store: rsacc rows already match oacc rows (quad*4+reg)
#pragma unroll
    for (int qs = 0; qs < 2; ++qs) {
        float inv[4];
#pragma unroll
        for (int reg = 0; reg < 4; ++reg) inv[reg] = 1.f / rsacc[qs][reg];
#pragma unroll
        for (int db = 0; db < 4; ++db)
#pragma unroll
            for (int reg = 0; reg < 4; ++reg) {
                const int row = tile0 + w * 32 + qs * 16 + quad * 4 + reg;
                const int col = h * 64 + db * 16 + l16;
                out[((size_t)(b * kN + row)) * kC + col] = f2bf(oacc[qs][db][reg] * inv[reg]);
            }
    }
}

// ------------------------------------------------------------------ launch
extern "C" void kernel_launch(void* const* d_in, const int* in_sizes, int n_in,
                              void* d_out, int out_size, void* d_ws, size_t ws_size,
                              hipStream_t stream)
{
    const float* x     = (const float*)d_in[0];
    const int*   mask  = (const int*)d_in[1];
    const float* Wqkv  = (const float*)d_in[2];
    const float* bqkv  = (const float*)d_in[3];
    const float* Wproj = (const float*)d_in[4];
    const float* bproj = (const float*)d_in[5];
    float* out = (float*)d_out;

    const size_t nx = (size_t)kB * kN * kC;
    const size_t qkv_elems = (size_t)kB * kH * kN * kD;
    u16* xb     = (u16*)d_ws;
    u16* qbuf   = xb + nx;
    u16* kbuf   = qbuf + qkv_elems;
    u16* vbuf   = kbuf + qkv_elems;
    u16* aob    = vbuf + qkv_elems;
    u16* Wqkvt  = aob + nx;
    u16* Wprojt = Wqkvt + (size_t)3 * kC * kC;
    u32* mbits  = (u32*)(Wprojt + (size_t)kC * kC);   // 2 MB bitmask

    maskpack_kernel<<<dim3(2048), dim3(256), 0, stream>>>(mask, mbits);
    cast_bf16_kernel<<<dim3(nx / 1024), dim3(256), 0, stream>>>(x, xb);
    tpose_cast_kernel<<<dim3(3 * kC / 64, kC / 64), dim3(256), 0, stream>>>(
        Wqkv, Wqkvt, kC, 3 * kC);
    tpose_cast_kernel<<<dim3(kC / 64, kC / 64), dim3(256), 0, stream>>>(
        Wproj, Wprojt, kC, kC);

    // 256^2 tiles: QKV grid 12*32 = 384, proj grid 4*32 = 128 (both %8==0)
    gemm256_kernel<1><<<dim3((3 * kC / 256) * (kB * kN / 256)), dim3(512), 0, stream>>>(
        xb, Wqkvt, bqkv, nullptr, qbuf, kbuf, vbuf, kB * kN, 3 * kC, kC);

    attn_mfma_kernel<<<dim3(kB * kH * (kN / 128)), dim3(256), 0, stream>>>(
        qbuf, kbuf, vbuf, mbits, aob);

    gemm256_kernel<0><<<dim3((kC / 256) * (kB * kN / 256)), dim3(512), 0, stream>>>(
        aob, Wprojt, bproj, out, nullptr, nullptr, nullptr, kB * kN, kC, kC);
}

// Round 10
// 359.932 us; speedup vs baseline: 1.0573x; 1.0573x over previous
//
#include <hip/hip_runtime.h>
#include <cstdint>
#include <cstddef>

constexpr int kC = 1024;   // DIM
constexpr int kH = 16;     // heads
constexpr int kB = 4;      // batch
constexpr int kN = 2048;   // seq
constexpr int kD = 64;     // head dim

// softmax scale folded into Q at the QKV-GEMM epilogue: 0.125 * log2(e)
#define KQ_SCALE 0.18033688011112042f

typedef unsigned short u16;
typedef unsigned int   u32;
typedef unsigned long long u64;
typedef __bf16 v8bf  __attribute__((ext_vector_type(8)));
typedef float  v4f   __attribute__((ext_vector_type(4)));
typedef u16    u16x8 __attribute__((ext_vector_type(8)));
typedef u16    u16x4 __attribute__((ext_vector_type(4)));
typedef u32    u32x2 __attribute__((ext_vector_type(2)));
typedef u32    u32x4 __attribute__((ext_vector_type(4)));

__device__ inline u16 f2bf(float f) {
    union { float f; unsigned u; } v; v.f = f;
    unsigned r = v.u + 0x7FFFu + ((v.u >> 16) & 1u);   // RNE
    return (u16)(r >> 16);
}

__device__ inline float fast_exp2(float x) {
#if __has_builtin(__builtin_amdgcn_exp2f)
    return __builtin_amdgcn_exp2f(x);          // bare v_exp_f32
#else
    return __expf(x * 0.6931471805599453f);
#endif
}

// async 16B global -> LDS (wave-uniform LDS base + lane*16)
__device__ inline void gl2lds16(const u16* g, u16* l) {
    __builtin_amdgcn_global_load_lds(
        (const __attribute__((address_space(1))) void*)g,
        (__attribute__((address_space(3))) void*)l, 16, 0, 0);
}

// ---------------------------------------------------------------- casts
__global__ __launch_bounds__(256) void cast_bf16_kernel(
    const float* __restrict__ in, u16* __restrict__ outp)
{
    const int i = blockIdx.x * 256 + threadIdx.x;
    const float4 f = ((const float4*)in)[i];
    u16x4 o;
    o.x = f2bf(f.x); o.y = f2bf(f.y); o.z = f2bf(f.z); o.w = f2bf(f.w);
    ((u16x4*)outp)[i] = o;
}

// W [R][Cc] fp32 -> Wt [Cc][R] bf16, 64x64 LDS tiles
__global__ __launch_bounds__(256) void tpose_cast_kernel(
    const float* __restrict__ W, u16* __restrict__ Wt, int R, int Cc)
{
    __shared__ u16 tile[64][65];
    const int c0 = blockIdx.x * 64;
    const int r0 = blockIdx.y * 64;
    const int t  = threadIdx.x;
#pragma unroll
    for (int it = 0; it < 16; ++it) {
        const int r = it * 4 + (t >> 6);
        const int c = t & 63;
        tile[c][r] = f2bf(W[(size_t)(r0 + r) * Cc + c0 + c]);
    }
    __syncthreads();
#pragma unroll
    for (int it = 0; it < 16; ++it) {
        const int rr = it * 4 + (t >> 6);
        const int cc = t & 63;
        Wt[(size_t)(c0 + rr) * R + r0 + cc] = tile[rr][cc];
    }
}

// ------------------------------------------------------------ mask pack
// Grid-strided: 2048 blocks. Row-bitmap: row (b*N+q) is 2048 bits
// (64 u32), bit k set iff masked. (R5-proven version.)
__global__ __launch_bounds__(256) void maskpack_kernel(
    const int* __restrict__ mask, u32* __restrict__ bits)
{
    const int lane = threadIdx.x & 63;
    const int wv   = threadIdx.x >> 6;
    const int nseg = kB * kN * 32;
    for (int seg = blockIdx.x * 4 + wv; seg < nseg; seg += gridDim.x * 4) {
        const size_t row = (size_t)(seg >> 5);   // b*N + q
        const int s = seg & 31;                  // 64-key segment within row
        const int m = mask[row * kN + s * 64 + lane];
        const u64 bal = __ballot(m != 0);
        if (lane == 0) ((u64*)bits)[row * 32 + s] = bal;
    }
}

// ---------------------------------------------------- bf16 MFMA GEMM
// C[M,N] = A[M,K] @ Bt[N,K]^T + bias.  128x128 tile, BK=32, 4 waves.
// 3-buffer / 2-ahead pipeline with COUNTED vmcnt + raw s_barrier (T3/T4).
// R5-proven config (best measured: non-attn 230.9 us) restored exactly.
template <int MODE>
__global__ __launch_bounds__(256, 3) void gemm_mfma_kernel(
    const u16* __restrict__ A, const u16* __restrict__ Bt,
    const float* __restrict__ bias, float* __restrict__ Cout,
    u16* __restrict__ qOut, u16* __restrict__ kOut, u16* __restrict__ vOut,
    int M, int N, int K)
{
    __shared__ u16 As0[128 * 32], Bs0[128 * 32];
    __shared__ u16 As1[128 * 32], Bs1[128 * 32];
    __shared__ u16 As2[128 * 32], Bs2[128 * 32];
    const int t    = threadIdx.x;
    const int w    = t >> 6;
    const int lane = t & 63;
    const int quad = lane >> 4;
    const int l16  = lane & 15;

    // XCD-chunked bijective swizzle (nwg % 8 == 0), column-major walk
    const int nby = M >> 7;
    const int q8  = (int)gridDim.x >> 3;
    const int bid = (int)blockIdx.x;
    const int swz = (bid & 7) * q8 + (bid >> 3);
    const int m0  = (swz % nby) * 128;
    const int n0  = (swz / nby) * 128;

    const int sr  = lane >> 2;                              // staging row in 16
    const int scs = ((lane & 3) ^ ((sr >> 1) & 3)) * 8;     // swizzled src chunk
    const u16* Ag0 = A  + (size_t)(m0 + 32 * w      + sr) * K + scs;
    const u16* Ag1 = A  + (size_t)(m0 + 32 * w + 16 + sr) * K + scs;
    const u16* Bg0 = Bt + (size_t)(n0 + 32 * w      + sr) * K + scs;
    const u16* Bg1 = Bt + (size_t)(n0 + 32 * w + 16 + sr) * K + scs;

    v4f acc[4][4];
#pragma unroll
    for (int r = 0; r < 4; ++r)
#pragma unroll
        for (int c = 0; c < 4; ++c) acc[r][c] = (v4f){0.f, 0.f, 0.f, 0.f};

    const int mrow = (w >> 1) * 64;
    const int ncol = (w & 1) * 64;
    const int pch  = (quad ^ ((l16 >> 1) & 3)) * 8;         // swizzled read chunk

    auto stage = [&](u16* Asb, u16* Bsb, int k0) {
        gl2lds16(Ag0 + k0, Asb + (32 * w) * 32);
        gl2lds16(Ag1 + k0, Asb + (32 * w + 16) * 32);
        gl2lds16(Bg0 + k0, Bsb + (32 * w) * 32);
        gl2lds16(Bg1 + k0, Bsb + (32 * w + 16) * 32);
    };
    auto compute = [&](const u16* Asb, const u16* Bsb) {
        v8bf af[4], bfr[4];
#pragma unroll
        for (int r = 0; r < 4; ++r)
            af[r] = *(const v8bf*)(Asb + (mrow + r * 16 + l16) * 32 + pch);
#pragma unroll
        for (int c = 0; c < 4; ++c)
            bfr[c] = *(const v8bf*)(Bsb + (ncol + c * 16 + l16) * 32 + pch);
        __builtin_amdgcn_s_setprio(1);
#pragma unroll
        for (int r = 0; r < 4; ++r)
#pragma unroll
            for (int c = 0; c < 4; ++c)
                acc[r][c] = __builtin_amdgcn_mfma_f32_16x16x32_bf16(
                    af[r], bfr[c], acc[r][c], 0, 0, 0);
        __builtin_amdgcn_s_setprio(0);
    };

    // prologue: 2 tiles in flight
    stage(As0, Bs0, 0);
    stage(As1, Bs1, 32);
    u16 *pa0 = As0, *pb0 = Bs0, *pa1 = As1, *pb1 = Bs1, *pa2 = As2, *pb2 = Bs2;

    for (int k0 = 0; k0 < K; k0 += 32) {
        if (k0 + 32 < K) {
            // tile t's 4 loads retired (tile t+1's 4 may remain in flight)
            asm volatile("s_waitcnt vmcnt(4)" ::: "memory");
        } else {
            asm volatile("s_waitcnt vmcnt(0)" ::: "memory");
        }
        __builtin_amdgcn_s_barrier();
        __builtin_amdgcn_sched_barrier(0);
        if (k0 + 64 < K) stage(pa2, pb2, k0 + 64);
        compute(pa0, pb0);
        u16* ta = pa0; pa0 = pa1; pa1 = pa2; pa2 = ta;
        u16* tb = pb0; pb0 = pb1; pb1 = pb2; pb2 = tb;
    }

#pragma unroll
    for (int r = 0; r < 4; ++r) {
#pragma unroll
        for (int c = 0; c < 4; ++c) {
            const int col = n0 + ncol + c * 16 + l16;
            const float bv = bias[col];
#pragma unroll
            for (int reg = 0; reg < 4; ++reg) {
                const int row = m0 + mrow + r * 16 + quad * 4 + reg;
                float val = acc[r][c][reg] + bv;
                if (MODE == 0) {
                    Cout[(size_t)row * N + col] = val;
                } else {
                    const int which = col >> 10;
                    const int rem   = col & 1023;
                    const int h     = rem >> 6;
                    const int d     = rem & 63;
                    const int b     = row >> 11;
                    const int n     = row & 2047;
                    if (which == 0) val *= KQ_SCALE;   // fold softmax scale + log2e into Q
                    u16* dst = (which == 0) ? qOut : (which == 1) ? kOut : vOut;
                    dst[(((size_t)(b * kH + h)) * kN + n) * kD + d] = f2bf(val);
                }
            }
        }
    }
}

// ------------------------------------------------- MFMA attention (bf16)
// R5/R8 structure (same LDS layouts, staging, mask path, MFMA order).
// THIS ROUND: VALU-diet only —
//  (a) swizzle algebra simplified so every LDS access is per-thread BASE +
//      compile-time constant: (nb*16+l16)&7 == l16&7 and (db*16+l16)&15 ==
//      l16, so S^T reads = Kr0/Kr1 + nb*1024, PV reads = Vrk + db*2048,
//      staging writes = 4 precomputed kt-invariant offsets each ->
//      compiler folds the constants into ds offset:N (zero per-access VALU;
//      measured VALUBusy 52% implied ~1180 VALU/wave/tile vs ~300 audited,
//      mostly recomputed XOR addresses).
//  (b) V reg-transpose via 16 explicit v_perm_b32 instead of elementwise
//      extract/insert (~64-96 VALU -> 16).
//  (c) S zero-init passed as MFMA C-in from a persistent zero v4f
//      (kills 64 v_mov/tile).
__global__ __launch_bounds__(256, 2) void attn_mfma_kernel(
    const u16* __restrict__ q, const u16* __restrict__ k,
    const u16* __restrict__ v, const u32* __restrict__ mbits,
    u16* __restrict__ out)   // bf16 ao [B,N,C]
{
    __shared__ u16 Ks[2][128 * 64];   // 32 KB  [key][d], chunk ^= (key&7)
    __shared__ u16 Vt[2][64 * 128];   // 32 KB  [d][key-permuted], chunk ^= (d&15)

    const int t    = threadIdx.x;
    const int w    = t >> 6;
    const int lane = t & 63;
    const int quad = lane >> 4;
    const int l16  = lane & 15;

    const int bh    = blockIdx.x >> 4;          // 16 q-tiles of 128 rows
    const int tile0 = (blockIdx.x & 15) * 128;
    const int b     = bh >> 4;
    const int h     = bh & 15;

    const u16* qb = q + (size_t)bh * kN * kD;
    const u16* kb = k + (size_t)bh * kN * kD;
    const u16* vb = v + (size_t)bh * kN * kD;

    // Q B-fragments for 2 strips: lane holds Q[qrow][d = quad*8 + j]
    const int qrow0 = tile0 + w * 32 + l16;
    const int qrow1 = qrow0 + 16;
    v8bf qf[2][2];
    qf[0][0] = *(const v8bf*)(qb + (size_t)qrow0 * kD + quad * 8);
    qf[0][1] = *(const v8bf*)(qb + (size_t)qrow0 * kD + 32 + quad * 8);
    qf[1][0] = *(const v8bf*)(qb + (size_t)qrow1 * kD + quad * 8);
    qf[1][1] = *(const v8bf*)(qb + (size_t)qrow1 * kD + 32 + quad * 8);

    // staging geometry (constant per thread)
    const int skr  = t >> 1;           // K row 0..127
    const int skh  = t & 1;            // K half (32 elems)
    const int vg   = t >> 4;           // frag chunk 0..15
    const int vdq  = t & 15;           // dim quad (dims vdq*4..+3)
    const int vrow0 = (vg >> 2) * 32 + (vg & 3) * 4;

    const u16* kp = kb + (size_t)skr * kD + skh * 32;
    const u16* vp = vb + (size_t)vrow0 * kD + vdq * 4;
    const uint4* mp0 = (const uint4*)(mbits + ((size_t)b * kN + qrow0) * 64);
    const uint4* mp1 = (const uint4*)(mbits + ((size_t)b * kN + qrow1) * 64);

    // ---- kt-invariant LDS element-offsets (swizzle algebra pre-folded) ----
    const int l7 = l16 & 7;
    const int kread0 = l16 * 64 + ((quad       ^ l7) * 8);   // + nb*1024
    const int kread1 = l16 * 64 + (((quad + 4) ^ l7) * 8);
    int vread[4];                                             // + db*2048
#pragma unroll
    for (int ks = 0; ks < 4; ++ks)
        vread[ks] = l16 * 128 + (((ks * 4 + quad) ^ l16) * 8);
    int kwrite[4];
#pragma unroll
    for (int i = 0; i < 4; ++i)
        kwrite[i] = skr * 64 + (((skh * 4 + i) ^ (skr & 7)) * 8);
    int vwrite[4];
#pragma unroll
    for (int dd = 0; dd < 4; ++dd)
        vwrite[dd] = (vdq * 4 + dd) * 128 + ((vg ^ ((vdq & 3) * 4 + dd)) * 8);

    u16x8 kpre[4];
    u16x4 vpre[8];
    uint4 mpre0, mpre1;
    auto issue_prefetch = [&]() {
#pragma unroll
        for (int i = 0; i < 4; ++i)
            kpre[i] = *(const u16x8*)(kp + i * 8);
#pragma unroll
        for (int i = 0; i < 8; ++i)
            vpre[i] = *(const u16x4*)(vp + (i < 4 ? i * 64 : 1024 + (i - 4) * 64));
        mpre0 = *mp0; mpre1 = *mp1;
        kp += 128 * kD; vp += 128 * kD; ++mp0; ++mp1;
    };

    v8bf onesf;
#pragma unroll
    for (int j = 0; j < 8; ++j) onesf[j] = (__bf16)1.0f;
    const v4f z4 = (v4f){0.f, 0.f, 0.f, 0.f};

    v4f oacc[2][4];
    v4f rsacc[2];
#pragma unroll
    for (int qs = 0; qs < 2; ++qs) {
        rsacc[qs] = (v4f){0.f, 0.f, 0.f, 0.f};
#pragma unroll
        for (int i = 0; i < 4; ++i) oacc[qs][i] = (v4f){0.f, 0.f, 0.f, 0.f};
    }

    issue_prefetch();   // tile 0

    for (int kt = 0; kt < kN / 128; ++kt) {
        u16* KsB = Ks[kt & 1];
        u16* VtB = Vt[kt & 1];

        // ---- stage tile kt from regs into buf[kt&1]
#pragma unroll
        for (int i = 0; i < 4; ++i)
            *(u16x8*)(KsB + kwrite[i]) = kpre[i];
        {
            // V transpose: 16 v_perm_b32 (verified: perm(hi,lo,0x05040100)
            // = lo.u16[0] | hi.u16[0]<<16 ; 0x07060302 selects u16[1])
            u32x2 vw[8];
#pragma unroll
            for (int j = 0; j < 8; ++j) vw[j] = __builtin_bit_cast(u32x2, vpre[j]);
#pragma unroll
            for (int dd = 0; dd < 4; ++dd) {
                const u32 sel = (dd & 1) ? 0x07060302u : 0x05040100u;
                const int hsel = dd >> 1;
                u32x4 col;
#pragma unroll
                for (int i = 0; i < 4; ++i)
                    col[i] = __builtin_amdgcn_perm(vw[2 * i + 1][hsel], vw[2 * i][hsel], sel);
                *(u32x4*)(VtB + vwrite[dd]) = col;
            }
        }
        const uint4 mc0 = mpre0, mc1 = mpre1;
        if (kt + 1 < kN / 128) issue_prefetch();   // regs free after ds_writes issue

        __syncthreads();   // publish buf[kt&1]; WAR covered by prev barrier

        const u32 mwa[2][4] = {{mc0.x, mc0.y, mc0.z, mc0.w},
                               {mc1.x, mc1.y, mc1.z, mc1.w}};
        v8bf pa[2][4];     // P A-fragments, built directly in registers

        const u16* Kr0 = KsB + kread0;
        const u16* Kr1 = KsB + kread1;

        // ---- S^T + softmax: lane gets s[reg] = S[key=nb*16+quad*4+reg][q=l16]
#pragma unroll
        for (int nb = 0; nb < 8; ++nb) {
            const v8bf kf0 = *(const v8bf*)(Kr0 + nb * 1024);
            const v8bf kf1 = *(const v8bf*)(Kr1 + nb * 1024);
#pragma unroll
            for (int qs = 0; qs < 2; ++qs) {
                v4f s = __builtin_amdgcn_mfma_f32_16x16x32_bf16(kf0, qf[qs][0], z4, 0, 0, 0);
                s = __builtin_amdgcn_mfma_f32_16x16x32_bf16(kf1, qf[qs][1], s, 0, 0, 0);

                const u32 m4 = (mwa[qs][nb >> 1] >> ((nb & 1) * 16 + quad * 4)) & 0xFu;
                float e0 = fast_exp2(s[0]);
                float e1 = fast_exp2(s[1]);
                float e2 = fast_exp2(s[2]);
                float e3 = fast_exp2(s[3]);
                e0 = (m4 & 1u) ? 0.f : e0;
                e1 = (m4 & 2u) ? 0.f : e1;
                e2 = (m4 & 4u) ? 0.f : e2;
                e3 = (m4 & 8u) ? 0.f : e3;

                pa[qs][nb >> 1][(nb & 1) * 4 + 0] = (__bf16)e0;
                pa[qs][nb >> 1][(nb & 1) * 4 + 1] = (__bf16)e1;
                pa[qs][nb >> 1][(nb & 1) * 4 + 2] = (__bf16)e2;
                pa[qs][nb >> 1][(nb & 1) * 4 + 3] = (__bf16)e3;
            }
        }

        __builtin_amdgcn_s_setprio(1);
        // row-sums via ones-MFMA: rsacc row layout == oacc row layout
#pragma unroll
        for (int qs = 0; qs < 2; ++qs)
#pragma unroll
            for (int ks = 0; ks < 4; ++ks)
                rsacc[qs] = __builtin_amdgcn_mfma_f32_16x16x32_bf16(
                    pa[qs][ks], onesf, rsacc[qs], 0, 0, 0);
        // ---- PV: O[q][d] += P(32x128) @ V^T
#pragma unroll
        for (int ks = 0; ks < 4; ++ks) {
            const u16* Vrk = VtB + vread[ks];
#pragma unroll
            for (int db = 0; db < 4; ++db) {
                const v8bf vf = *(const v8bf*)(Vrk + db * 2048);
#pragma unroll
                for (int qs = 0; qs < 2; ++qs)
                    oacc[qs][db] = __builtin_amdgcn_mfma_f32_16x16x32_bf16(
                        pa[qs][ks], vf, oacc[qs][db], 0, 0, 0);
            }
        }
        __builtin_amdgcn_s_setprio(0);
    }

    // ---- normalize + store: rsacc rows already match oacc rows (quad*4+reg)
#pragma unroll
    for (int qs = 0; qs < 2; ++qs) {
        float inv[4];
#pragma unroll
        for (int reg = 0; reg < 4; ++reg) inv[reg] = 1.f / rsacc[qs][reg];
#pragma unroll
        for (int db = 0; db < 4; ++db)
#pragma unroll
            for (int reg = 0; reg < 4; ++reg) {
                const int row = tile0 + w * 32 + qs * 16 + quad * 4 + reg;
                const int col = h * 64 + db * 16 + l16;
                out[((size_t)(b * kN + row)) * kC + col] = f2bf(oacc[qs][db][reg] * inv[reg]);
            }
    }
}

// ------------------------------------------------------------------ launch
extern "C" void kernel_launch(void* const* d_in, const int* in_sizes, int n_in,
                              void* d_out, int out_size, void* d_ws, size_t ws_size,
                              hipStream_t stream)
{
    const float* x     = (const float*)d_in[0];
    const int*   mask  = (const int*)d_in[1];
    const float* Wqkv  = (const float*)d_in[2];
    const float* bqkv  = (const float*)d_in[3];
    const float* Wproj = (const float*)d_in[4];
    const float* bproj = (const float*)d_in[5];
    float* out = (float*)d_out;

    const size_t nx = (size_t)kB * kN * kC;
    const size_t qkv_elems = (size_t)kB * kH * kN * kD;
    u16* xb     = (u16*)d_ws;
    u16* qbuf   = xb + nx;
    u16* kbuf   = qbuf + qkv_elems;
    u16* vbuf   = kbuf + qkv_elems;
    u16* aob    = vbuf + qkv_elems;
    u16* Wqkvt  = aob + nx;
    u16* Wprojt = Wqkvt + (size_t)3 * kC * kC;
    u32* mbits  = (u32*)(Wprojt + (size_t)kC * kC);   // 2 MB bitmask

    maskpack_kernel<<<dim3(2048), dim3(256), 0, stream>>>(mask, mbits);
    cast_bf16_kernel<<<dim3(nx / 1024), dim3(256), 0, stream>>>(x, xb);
    tpose_cast_kernel<<<dim3(3 * kC / 64, kC / 64), dim3(256), 0, stream>>>(
        Wqkv, Wqkvt, kC, 3 * kC);
    tpose_cast_kernel<<<dim3(kC / 64, kC / 64), dim3(256), 0, stream>>>(
        Wproj, Wprojt, kC, kC);

    // 1-D grids (XCD swizzle inside): nwg = (N/128)*(M/128), % 8 == 0
    gemm_mfma_kernel<1><<<dim3((3 * kC / 128) * (kB * kN / 128)), dim3(256), 0, stream>>>(
        xb, Wqkvt, bqkv, nullptr, qbuf, kbuf, vbuf, kB * kN, 3 * kC, kC);

    attn_mfma_kernel<<<dim3(kB * kH * (kN / 128)), dim3(256), 0, stream>>>(
        qbuf, kbuf, vbuf, mbits, aob);

    gemm_mfma_kernel<0><<<dim3((kC / 128) * (kB * kN / 128)), dim3(256), 0, stream>>>(
        aob, Wprojt, bproj, out, nullptr, nullptr, nullptr, kB * kN, kC, kC);
}